// Round 6
// baseline (209.605 us; speedup 1.0000x reference)
//
#include <hip/hip_runtime.h>

#define B_ROWS 8192
#define D_IN   1024
#define NOUT   1024
#define NB     8
#define KTOT   (D_IN * (NB + 1))   // 9216
#define GM     256
#define GN     128
#define GK     64

typedef __attribute__((ext_vector_type(4))) float f32x4;
typedef __attribute__((ext_vector_type(8))) short bf16x8;

__device__ __forceinline__ unsigned short f2bf(float f) {
  union { float f; unsigned u; } v; v.f = f;
  unsigned r = v.u + 0x7fffu + ((v.u >> 16) & 1u);   // RNE
  return (unsigned short)(r >> 16);
}

__device__ __forceinline__ void load_lds16(const void* g, void* l) {
  __builtin_amdgcn_global_load_lds(
      (const __attribute__((address_space(1))) unsigned int*)g,
      (__attribute__((address_space(3))) unsigned int*)l, 16, 0, 0);
}

__device__ __forceinline__ void barrier_raw() {
  asm volatile("" ::: "memory");
  __builtin_amdgcn_s_barrier();
  asm volatile("" ::: "memory");
}

// ---------------- weights -> bf16, concatenated [NOUT][KTOT] ----------------
__global__ __launch_bounds__(256) void wconv_kernel(
    const float* __restrict__ bw, const float* __restrict__ sw,
    unsigned short* __restrict__ Wc) {
  const size_t idx = ((size_t)blockIdx.x * 256 + threadIdx.x) * 4;
  const int n = (int)(idx / KTOT);
  const int k = (int)(idx % KTOT);
  float4 f;
  if (k < D_IN)
    f = *reinterpret_cast<const float4*>(bw + (size_t)n * D_IN + k);
  else
    f = *reinterpret_cast<const float4*>(sw + (size_t)n * (D_IN * NB) + (k - D_IN));
  union { unsigned short us[4]; uint2 u2; } o;
  o.us[0] = f2bf(f.x); o.us[1] = f2bf(f.y); o.us[2] = f2bf(f.z); o.us[3] = f2bf(f.w);
  *reinterpret_cast<uint2*>(Wc + idx) = o.u2;
}

// ------------- LayerNorm + silu + (spline + rbf) feature matrix -------------
__global__ __launch_bounds__(256) void feat_kernel(
    const float* __restrict__ x, const float* __restrict__ lnw,
    const float* __restrict__ lnb, unsigned short* __restrict__ F, int row0) {
  const int row = row0 + blockIdx.x;
  const float* xr = x + (size_t)row * D_IN;
  const int t = threadIdx.x;
  float v[4];
  float s = 0.f, s2 = 0.f;
#pragma unroll
  for (int i = 0; i < 4; ++i) {
    v[i] = xr[t + 256 * i];
    s += v[i];
    s2 += v[i] * v[i];
  }
#pragma unroll
  for (int off = 32; off > 0; off >>= 1) {
    s += __shfl_xor(s, off);
    s2 += __shfl_xor(s2, off);
  }
  __shared__ float red[8];
  const int wid = t >> 6;
  if ((t & 63) == 0) { red[wid] = s; red[4 + wid] = s2; }
  __syncthreads();
  s  = red[0] + red[1] + red[2] + red[3];
  s2 = red[4] + red[5] + red[6] + red[7];
  const float mu = s * (1.f / D_IN);
  const float var = s2 * (1.f / D_IN) - mu * mu;
  const float rstd = rsqrtf(var + 1e-5f);
  unsigned short* Frow = F + (size_t)blockIdx.x * KTOT;
#pragma unroll
  for (int i = 0; i < 4; ++i) {
    const int d = t + 256 * i;
    const float xn = (v[i] - mu) * rstd * lnw[d] + lnb[d];
    Frow[d] = f2bf(xn / (1.f + __expf(-xn)));           // SiLU
    float b[11];
#pragma unroll
    for (int j = 0; j < 11; ++j) {
      const float gj = 0.6f * j - 3.3f;
      b[j] = (xn >= gj && xn < gj + 0.6f) ? 1.f : 0.f;
    }
#pragma unroll
    for (int k = 1; k <= 3; ++k) {
      const float inv = 1.f / (0.6f * k);
#pragma unroll
      for (int j = 0; j <= 10 - k; ++j) {
        const float gj = 0.6f * j - 3.3f;
        b[j] = (xn - gj) * inv * b[j] + (gj + 0.6f * (k + 1) - xn) * inv * b[j + 1];
      }
    }
    union { unsigned short us[8]; uint4 u4; } pk;
#pragma unroll
    for (int j = 0; j < 8; ++j) {
      const float c = -1.5f + (3.f / 7.f) * j;
      const float tt = (xn - c) * (7.f / 3.f);
      pk.us[j] = f2bf(b[j] + __expf(-tt * tt));
    }
    *reinterpret_cast<uint4*>(Frow + D_IN + (size_t)d * 8) = pk.u4;
  }
}

// ---- GEMM: C = F @ Wc^T, 256x128 tile, ring-3 LDS, 1 barrier / K-tile ----
// 8 waves = (wm2 x wn2 x wk2): wave tile 128x64, K-split across wk.
__global__ __launch_bounds__(512, 2) void gemm_kernel(
    const unsigned short* __restrict__ A, const unsigned short* __restrict__ Bw,
    float* __restrict__ C, int row0) {
  __shared__ char smem[147456];                         // 144 KB
  unsigned short* AsBase = (unsigned short*)smem;       // 3 x 32 KB
  unsigned short* BsBase = (unsigned short*)(smem + 98304);  // 3 x 16 KB
  const int t = threadIdx.x;
  const int w = t >> 6, l = t & 63;
  const int wr = w >> 2, wc2 = (w >> 1) & 1, wk = w & 1;
  const int id = blockIdx.x;
  const int nbm = gridDim.x >> 3;             // grid = nbm * 8
  int bm, bn;
  if ((nbm & 7) == 0) {
    const int c = id & 7, j = id >> 3, q = nbm >> 3;
    bm = c + 8 * (j % q);                     // bm%8 == XCD id -> A-panel sharers co-XCD
    bn = j / q;
  } else {
    bm = id % nbm; bn = id / nbm;
  }
  const size_t Abase = (size_t)bm * GM * KTOT;
  const size_t Bbase = (size_t)bn * GN * KTOT;

  const int arow = l >> 3;             // row within an 8-row segment
  const int achk = (l & 7) ^ arow;     // pre-swizzled source chunk (T2 write side)

  f32x4 acc[8][4] = {};

  auto stageA = [&](int buf, int k0) {
#pragma unroll
    for (int i = 0; i < 4; ++i) {
      const int seg = w * 4 + i;                           // 8 rows per segment
      load_lds16(A + Abase + (size_t)(seg * 8 + arow) * KTOT + k0 + achk * 8,
                 (char*)(AsBase + buf * 16384) + seg * 1024);
    }
  };
  auto stageB = [&](int buf, int k0) {
#pragma unroll
    for (int i = 0; i < 2; ++i) {
      const int seg = w * 2 + i;
      load_lds16(Bw + Bbase + (size_t)(seg * 8 + arow) * KTOT + k0 + achk * 8,
                 (char*)(BsBase + buf * 8192) + seg * 1024);
    }
  };

  const int hi = l >> 4, rs = l & 7, l15 = l & 15;
  const int cb = ((wk * 4 + hi) ^ rs) * 16;   // swizzled chunk byte offset (fixed per lane)

  auto dsread = [&](int buf, bf16x8* a, bf16x8* b) {
    const char* Asb = (const char*)(AsBase + buf * 16384);
    const char* Bsb = (const char*)(BsBase + buf * 8192);
#pragma unroll
    for (int n = 0; n < 4; ++n)
      b[n] = *reinterpret_cast<const bf16x8*>(Bsb + (wc2 * 64 + n * 16 + l15) * 128 + cb);
#pragma unroll
    for (int m = 0; m < 8; ++m)
      a[m] = *reinterpret_cast<const bf16x8*>(Asb + (wr * 128 + m * 16 + l15) * 128 + cb);
  };
  auto domfma = [&](bf16x8* a, bf16x8* b) {
    __builtin_amdgcn_s_setprio(1);
#pragma unroll
    for (int m = 0; m < 8; ++m)
#pragma unroll
      for (int n = 0; n < 4; ++n)
        acc[m][n] = __builtin_amdgcn_mfma_f32_16x16x32_bf16(a[m], b[n], acc[m][n], 0, 0, 0);
    __builtin_amdgcn_s_setprio(0);
  };

  const int NT = KTOT / GK;            // 144
  stageA(0, 0); stageB(0, 0);
  stageA(1, GK); stageB(1, GK);
  asm volatile("s_waitcnt vmcnt(6)" ::: "memory");
  barrier_raw();

  int cur = 0;
  for (int tt = 0; tt < NT; ++tt) {
    int pre = cur + 2; if (pre >= 3) pre -= 3;
    const bool have2 = (tt + 2 < NT);
    bf16x8 a[8], b[4];
    // All LDS reads for this wave's kk-slice + tile tt+2's stages up front;
    // reads and global_load_lds traffic complete under the MFMA cluster.
    dsread(cur, a, b);
    if (have2) { stageA(pre, (tt + 2) * GK); stageB(pre, (tt + 2) * GK); }
    __builtin_amdgcn_sched_barrier(0);
    domfma(a, b);              // compiler inserts fine-grained lgkmcnt waits
    if (tt + 1 < NT) {
      if (have2)
        asm volatile("s_waitcnt vmcnt(6)" ::: "memory");  // tile tt+1 landed; tt+2 in flight
      else
        asm volatile("s_waitcnt vmcnt(0)" ::: "memory");  // epilogue drain
      barrier_raw();           // all waves done reading cur; tile tt+1 visible
    }
    cur = cur + 1; if (cur >= 3) cur = 0;
  }

  // ---- epilogue: reduce wk pairs through LDS, wk==0 writes C ----
  barrier_raw();                         // everyone done with the ring
  float* red = (float*)smem;             // 128 KB scratch
  const int region = (wr * 2 + wc2) * 8192;   // floats
  if (wk == 1) {
#pragma unroll
    for (int m = 0; m < 8; ++m)
#pragma unroll
      for (int n = 0; n < 4; ++n)
        *reinterpret_cast<f32x4*>(red + region + ((m * 4 + n) * 64 + l) * 4) = acc[m][n];
  }
  barrier_raw();
  if (wk == 0) {
    const int crow0 = row0 + bm * GM + wr * 128 + hi * 4;
    const int ccol0 = bn * GN + wc2 * 64 + l15;
#pragma unroll
    for (int m = 0; m < 8; ++m)
#pragma unroll
      for (int n = 0; n < 4; ++n) {
        f32x4 o = *reinterpret_cast<const f32x4*>(red + region + ((m * 4 + n) * 64 + l) * 4);
        o += acc[m][n];
        float* cp = C + (size_t)(crow0 + m * 16) * NOUT + ccol0 + n * 16;
#pragma unroll
        for (int r = 0; r < 4; ++r)
          cp[(size_t)r * NOUT] = o[r];
      }
  }
}

extern "C" void kernel_launch(void* const* d_in, const int* in_sizes, int n_in,
                              void* d_out, int out_size, void* d_ws, size_t ws_size,
                              hipStream_t stream) {
  const float* x   = (const float*)d_in[0];
  const float* lnw = (const float*)d_in[1];
  const float* lnb = (const float*)d_in[2];
  const float* bw  = (const float*)d_in[3];
  const float* sw  = (const float*)d_in[4];
  float* out = (float*)d_out;
  char* ws = (char*)d_ws;

  const size_t wc_bytes = (size_t)NOUT * KTOT * 2;   // ~18.9 MB
  unsigned short* Wc = (unsigned short*)ws;
  unsigned short* F  = (unsigned short*)(ws + wc_bytes);

  size_t avail = (ws_size > wc_bytes) ? ws_size - wc_bytes : 0;
  long long cm = (long long)(avail / ((size_t)KTOT * 2));
  cm &= ~255LL;
  if (cm < 256) cm = 256;
  if (cm > B_ROWS) cm = B_ROWS;
  const int chunkM = (int)cm;

  wconv_kernel<<<(NOUT * (KTOT / 4)) / 256, 256, 0, stream>>>(bw, sw, Wc);
  for (int r0 = 0; r0 < B_ROWS; r0 += chunkM) {
    int rows = B_ROWS - r0; if (rows > chunkM) rows = chunkM;
    feat_kernel<<<rows, 256, 0, stream>>>(x, lnw, lnb, F, r0);
    gemm_kernel<<<dim3((rows / GM) * (NOUT / GN)), 512, 0, stream>>>(F, Wc, out, r0);
  }
}

// Round 7
// 207.670 us; speedup vs baseline: 1.0093x; 1.0093x over previous
//
#include <hip/hip_runtime.h>

#define B_ROWS 8192
#define D_IN   1024
#define NOUT   1024
#define NB     8
#define KTOT   (D_IN * (NB + 1))   // 9216
#define GM     256
#define GN     128
#define GK     64

typedef __attribute__((ext_vector_type(4))) float f32x4;
typedef __attribute__((ext_vector_type(8))) short bf16x8;

__device__ __forceinline__ unsigned short f2bf(float f) {
  union { float f; unsigned u; } v; v.f = f;
  unsigned r = v.u + 0x7fffu + ((v.u >> 16) & 1u);   // RNE
  return (unsigned short)(r >> 16);
}

__device__ __forceinline__ void load_lds16(const void* g, void* l) {
  __builtin_amdgcn_global_load_lds(
      (const __attribute__((address_space(1))) unsigned int*)g,
      (__attribute__((address_space(3))) unsigned int*)l, 16, 0, 0);
}

__device__ __forceinline__ void barrier_raw() {
  asm volatile("" ::: "memory");
  __builtin_amdgcn_s_barrier();
  asm volatile("" ::: "memory");
}

// ---------------- weights -> bf16, concatenated [NOUT][KTOT] ----------------
__global__ __launch_bounds__(256) void wconv_kernel(
    const float* __restrict__ bw, const float* __restrict__ sw,
    unsigned short* __restrict__ Wc) {
  const size_t idx = ((size_t)blockIdx.x * 256 + threadIdx.x) * 4;
  const int n = (int)(idx / KTOT);
  const int k = (int)(idx % KTOT);
  float4 f;
  if (k < D_IN)
    f = *reinterpret_cast<const float4*>(bw + (size_t)n * D_IN + k);
  else
    f = *reinterpret_cast<const float4*>(sw + (size_t)n * (D_IN * NB) + (k - D_IN));
  union { unsigned short us[4]; uint2 u2; } o;
  o.us[0] = f2bf(f.x); o.us[1] = f2bf(f.y); o.us[2] = f2bf(f.z); o.us[3] = f2bf(f.w);
  *reinterpret_cast<uint2*>(Wc + idx) = o.u2;
}

// ------------- LayerNorm + silu + (spline + rbf) feature matrix -------------
__global__ __launch_bounds__(256) void feat_kernel(
    const float* __restrict__ x, const float* __restrict__ lnw,
    const float* __restrict__ lnb, unsigned short* __restrict__ F, int row0) {
  const int row = row0 + blockIdx.x;
  const float* xr = x + (size_t)row * D_IN;
  const int t = threadIdx.x;
  float v[4];
  float s = 0.f, s2 = 0.f;
#pragma unroll
  for (int i = 0; i < 4; ++i) {
    v[i] = xr[t + 256 * i];
    s += v[i];
    s2 += v[i] * v[i];
  }
#pragma unroll
  for (int off = 32; off > 0; off >>= 1) {
    s += __shfl_xor(s, off);
    s2 += __shfl_xor(s2, off);
  }
  __shared__ float red[8];
  const int wid = t >> 6;
  if ((t & 63) == 0) { red[wid] = s; red[4 + wid] = s2; }
  __syncthreads();
  s  = red[0] + red[1] + red[2] + red[3];
  s2 = red[4] + red[5] + red[6] + red[7];
  const float mu = s * (1.f / D_IN);
  const float var = s2 * (1.f / D_IN) - mu * mu;
  const float rstd = rsqrtf(var + 1e-5f);
  unsigned short* Frow = F + (size_t)blockIdx.x * KTOT;
#pragma unroll
  for (int i = 0; i < 4; ++i) {
    const int d = t + 256 * i;
    const float xn = (v[i] - mu) * rstd * lnw[d] + lnb[d];
    Frow[d] = f2bf(xn / (1.f + __expf(-xn)));           // SiLU
    float b[11];
#pragma unroll
    for (int j = 0; j < 11; ++j) {
      const float gj = 0.6f * j - 3.3f;
      b[j] = (xn >= gj && xn < gj + 0.6f) ? 1.f : 0.f;
    }
#pragma unroll
    for (int k = 1; k <= 3; ++k) {
      const float inv = 1.f / (0.6f * k);
#pragma unroll
      for (int j = 0; j <= 10 - k; ++j) {
        const float gj = 0.6f * j - 3.3f;
        b[j] = (xn - gj) * inv * b[j] + (gj + 0.6f * (k + 1) - xn) * inv * b[j + 1];
      }
    }
    union { unsigned short us[8]; uint4 u4; } pk;
#pragma unroll
    for (int j = 0; j < 8; ++j) {
      const float c = -1.5f + (3.f / 7.f) * j;
      const float tt = (xn - c) * (7.f / 3.f);
      pk.us[j] = f2bf(b[j] + __expf(-tt * tt));
    }
    *reinterpret_cast<uint4*>(Frow + D_IN + (size_t)d * 8) = pk.u4;
  }
}

// ---- GEMM: C = F @ Wc^T, 256x128 tile, ring-3 LDS, pipelined frag reads ----
// A = F [rows][KTOT] bf16, Bw = Wc [NOUT][KTOT] bf16. 8 waves: 4M x 2N.
__global__ __launch_bounds__(512, 2) void gemm_kernel(
    const unsigned short* __restrict__ A, const unsigned short* __restrict__ Bw,
    float* __restrict__ C, int row0) {
  __shared__ unsigned short As[3][GM * GK];   // 3 x 32 KB
  __shared__ unsigned short Bs[3][GN * GK];   // 3 x 16 KB
  const int t = threadIdx.x;
  const int w = t >> 6, l = t & 63;
  const int wr = w >> 1, wc = w & 1;          // 4 x 2 waves, 64x64 each
  const int id = blockIdx.x;
  const int nbm = gridDim.x >> 3;             // grid = nbm * 8
  int bm, bn;
  if ((nbm & 7) == 0) {
    const int c = id & 7, j = id >> 3, q = nbm >> 3;
    bm = c + 8 * (j % q);                     // bm%8 == XCD id -> A-panel sharers co-XCD
    bn = j / q;
  } else {
    bm = id % nbm; bn = id / nbm;
  }
  const size_t Abase = (size_t)bm * GM * KTOT;
  const size_t Bbase = (size_t)bn * GN * KTOT;

  const int arow = l >> 3;             // row within an 8-row segment
  const int achk = (l & 7) ^ arow;     // pre-swizzled source chunk (T2 write side)

  f32x4 acc[4][4] = {};

  auto stageA = [&](int buf, int k0) {
#pragma unroll
    for (int i = 0; i < 4; ++i) {
      const int seg = w * 4 + i;                           // 8 rows per segment
      load_lds16(A + Abase + (size_t)(seg * 8 + arow) * KTOT + k0 + achk * 8,
                 (char*)&As[buf][0] + seg * 1024);
    }
  };
  auto stageB = [&](int buf, int k0) {
#pragma unroll
    for (int i = 0; i < 2; ++i) {
      const int seg = w * 2 + i;
      load_lds16(Bw + Bbase + (size_t)(seg * 8 + arow) * KTOT + k0 + achk * 8,
                 (char*)&Bs[buf][0] + seg * 1024);
    }
  };

  const int hi = l >> 4;
  const int rA = wr * 64 + (l & 15);
  const int rB = wc * 64 + (l & 15);
  const int rs = l & 7;                // == row&7 for fragment reads

  auto dsread = [&](int buf, int kk, bf16x8* a, bf16x8* b) {
    const int cb = ((kk * 4 + hi) ^ rs) * 16;   // swizzled chunk byte offset (T2 read side)
#pragma unroll
    for (int m = 0; m < 4; ++m)
      a[m] = *reinterpret_cast<const bf16x8*>(
          (const char*)&As[buf][0] + (rA + m * 16) * 128 + cb);
#pragma unroll
    for (int n = 0; n < 4; ++n)
      b[n] = *reinterpret_cast<const bf16x8*>(
          (const char*)&Bs[buf][0] + (rB + n * 16) * 128 + cb);
  };
  auto domfma = [&](bf16x8* a, bf16x8* b) {
    __builtin_amdgcn_s_setprio(1);
#pragma unroll
    for (int m = 0; m < 4; ++m)
#pragma unroll
      for (int n = 0; n < 4; ++n)
        acc[m][n] = __builtin_amdgcn_mfma_f32_16x16x32_bf16(a[m], b[n], acc[m][n], 0, 0, 0);
    __builtin_amdgcn_s_setprio(0);
  };

  const int NT = KTOT / GK;            // 144
  // prologue: 2 tiles in flight, wait the first, preload kk0 frags of tile 0
  stageA(0, 0); stageB(0, 0);
  stageA(1, GK); stageB(1, GK);
  asm volatile("s_waitcnt vmcnt(6)" ::: "memory");
  barrier_raw();

  bf16x8 a0[4], b0[4], a1[4], b1[4];
  dsread(0, 0, a0, b0);
  int cur = 0;
  for (int tt = 0; tt < NT; ++tt) {
    int pre = cur + 2; if (pre >= 3) pre -= 3;
    int nxt = cur + 1; if (nxt >= 3) nxt -= 3;
    const bool have2 = (tt + 2 < NT);
    // issue kk1 frag reads + tile tt+2 staging; both complete under MFMA(kk0)
    dsread(cur, 1, a1, b1);
    if (have2) { stageA(pre, (tt + 2) * GK); stageB(pre, (tt + 2) * GK); }
    __builtin_amdgcn_sched_barrier(0);
    domfma(a0, b0);
    __builtin_amdgcn_sched_barrier(0);
    if (tt + 1 < NT) {
      if (have2)
        asm volatile("s_waitcnt vmcnt(6) lgkmcnt(0)" ::: "memory");  // tt+1 landed; kk1 reads done
      else
        asm volatile("s_waitcnt vmcnt(0) lgkmcnt(0)" ::: "memory");  // epilogue drain
      barrier_raw();
      // next tile's kk0 frag reads; complete under MFMA(kk1)
      dsread(nxt, 0, a0, b0);
      __builtin_amdgcn_sched_barrier(0);
    }
    domfma(a1, b1);
    cur = nxt;
  }

  const int crow0 = row0 + bm * GM + wr * 64 + hi * 4;
  const int ccol0 = bn * GN + wc * 64 + (l & 15);
#pragma unroll
  for (int m = 0; m < 4; ++m)
#pragma unroll
    for (int n = 0; n < 4; ++n) {
      float* cp = C + (size_t)(crow0 + m * 16) * NOUT + ccol0 + n * 16;
#pragma unroll
      for (int r = 0; r < 4; ++r)
        cp[(size_t)r * NOUT] = acc[m][n][r];
    }
}

extern "C" void kernel_launch(void* const* d_in, const int* in_sizes, int n_in,
                              void* d_out, int out_size, void* d_ws, size_t ws_size,
                              hipStream_t stream) {
  const float* x   = (const float*)d_in[0];
  const float* lnw = (const float*)d_in[1];
  const float* lnb = (const float*)d_in[2];
  const float* bw  = (const float*)d_in[3];
  const float* sw  = (const float*)d_in[4];
  float* out = (float*)d_out;
  char* ws = (char*)d_ws;

  const size_t wc_bytes = (size_t)NOUT * KTOT * 2;   // ~18.9 MB
  unsigned short* Wc = (unsigned short*)ws;
  unsigned short* F  = (unsigned short*)(ws + wc_bytes);

  size_t avail = (ws_size > wc_bytes) ? ws_size - wc_bytes : 0;
  long long cm = (long long)(avail / ((size_t)KTOT * 2));
  cm &= ~255LL;
  if (cm < 256) cm = 256;
  if (cm > B_ROWS) cm = B_ROWS;
  const int chunkM = (int)cm;

  wconv_kernel<<<(NOUT * (KTOT / 4)) / 256, 256, 0, stream>>>(bw, sw, Wc);
  for (int r0 = 0; r0 < B_ROWS; r0 += chunkM) {
    int rows = B_ROWS - r0; if (rows > chunkM) rows = chunkM;
    feat_kernel<<<rows, 256, 0, stream>>>(x, lnw, lnb, F, r0);
    gemm_kernel<<<dim3((rows / GM) * (NOUT / GN)), 512, 0, stream>>>(F, Wc, out, r0);
  }
}